// Round 1
// baseline (1000.531 us; speedup 1.0000x reference)
//
#include <hip/hip_runtime.h>
#include <math.h>

#define D_MODEL   768
#define N_FEAT    32768
#define K_TOP     64
#define AUX_K     128
#define BATCH     1024
#define DEAD_AFTER 1000
#define AUX_COEFF 0.03125f
#define CAP       2048

__device__ __forceinline__ unsigned sortable(float f) {
    unsigned u = __float_as_uint(f);
    return u ^ ((unsigned)((int)u >> 31) | 0x80000000u);
}
__device__ __forceinline__ float unsortable(unsigned s) {
    unsigned u = (s & 0x80000000u) ? (s ^ 0x80000000u) : ~s;
    return __uint_as_float(u);
}

// ---------------------------------------------------------------- prep
__global__ __launch_bounds__(256) void k_prep(
    const float* __restrict__ x, const float* __restrict__ b_pre,
    const float* __restrict__ b_post, const float* __restrict__ avg_norm,
    float* __restrict__ xn, float* __restrict__ enc_in, float* __restrict__ scal) {
    if (blockIdx.x == 0 && threadIdx.x == 0) { scal[0] = 0.f; scal[1] = 0.f; }
    const float s = sqrtf((float)D_MODEL) / avg_norm[0];
    const int n = BATCH * D_MODEL;
    for (int i = blockIdx.x * blockDim.x + threadIdx.x; i < n; i += gridDim.x * blockDim.x) {
        int d = i % D_MODEL;
        float v = x[i] * s;
        xn[i] = v;
        enc_in[i] = v - b_post[d] + b_pre[d];
    }
}

// ---------------------------------------------------------------- f32 SGEMM
// C[1024][32768] = A[1024][768] @ B[768][32768]; 128x128 tile, BK=8, 8x8 micro.
__global__ __launch_bounds__(256) void k_gemm(
    const float* __restrict__ A, const float* __restrict__ B, float* __restrict__ C) {
    __shared__ float As[8][128];
    __shared__ float Bs[8][128];
    const int t  = threadIdx.x;
    const int bx = blockIdx.x;   // N/128 = 256
    const int by = blockIdx.y;   // M/128 = 8
    const int tx = t & 15;
    const int ty = t >> 4;
    const int arow = t >> 1;           // 0..127
    const int acol = (t & 1) << 2;     // 0 or 4
    const int brow = t >> 5;           // 0..7
    const int bcol = (t & 31) << 2;    // 0..124
    const float* Ap = A + (size_t)(by * 128 + arow) * D_MODEL + acol;
    const float* Bp = B + (size_t)brow * N_FEAT + bx * 128 + bcol;

    float acc[8][8];
#pragma unroll
    for (int i = 0; i < 8; i++)
#pragma unroll
        for (int j = 0; j < 8; j++) acc[i][j] = 0.f;

    float4 av = *(const float4*)(Ap);
    float4 bv = *(const float4*)(Bp);

    for (int k0 = 0; k0 < D_MODEL; k0 += 8) {
        __syncthreads();
        As[acol + 0][arow] = av.x;
        As[acol + 1][arow] = av.y;
        As[acol + 2][arow] = av.z;
        As[acol + 3][arow] = av.w;
        *(float4*)&Bs[brow][bcol] = bv;
        __syncthreads();
        if (k0 + 8 < D_MODEL) {   // prefetch next tile while computing this one
            av = *(const float4*)(Ap + k0 + 8);
            bv = *(const float4*)(Bp + (size_t)(k0 + 8) * N_FEAT);
        }
#pragma unroll
        for (int k = 0; k < 8; k++) {
            float a[8], bb[8];
            *(float4*)&a[0]  = *(const float4*)&As[k][ty * 8];
            *(float4*)&a[4]  = *(const float4*)&As[k][ty * 8 + 4];
            *(float4*)&bb[0] = *(const float4*)&Bs[k][tx * 8];
            *(float4*)&bb[4] = *(const float4*)&Bs[k][tx * 8 + 4];
#pragma unroll
            for (int i = 0; i < 8; i++)
#pragma unroll
                for (int j = 0; j < 8; j++)
                    acc[i][j] = fmaf(a[i], bb[j], acc[i][j]);
        }
    }
#pragma unroll
    for (int i = 0; i < 8; i++) {
        size_t row = (size_t)(by * 128 + ty * 8 + i);
        float* Cp = C + row * N_FEAT + bx * 128 + tx * 8;
        *(float4*)Cp       = make_float4(acc[i][0], acc[i][1], acc[i][2], acc[i][3]);
        *(float4*)(Cp + 4) = make_float4(acc[i][4], acc[i][5], acc[i][6], acc[i][7]);
    }
}

// ---------------------------------------------------------------- exact top-k per row
__global__ __launch_bounds__(256) void k_topk(
    const float* __restrict__ enc, const float* __restrict__ enc_in,
    const int* __restrict__ activated,
    int* __restrict__ tidx, float* __restrict__ tw,
    int* __restrict__ aidx, float* __restrict__ aw, float* __restrict__ scal) {
    const int b = blockIdx.x;
    const int t = threadIdx.x;
    __shared__ unsigned long long cand[CAP];
    __shared__ float red[4];
    __shared__ int sh_cnt;
    __shared__ int sh_m;
    __shared__ float sh_sigma;

    // exact per-row sigma from ||enc_in_b||
    float ss = 0.f;
    for (int d = t; d < D_MODEL; d += 256) { float v = enc_in[(size_t)b * D_MODEL + d]; ss += v * v; }
    for (int off = 32; off > 0; off >>= 1) ss += __shfl_down(ss, off, 64);
    if ((t & 63) == 0) red[t >> 6] = ss;
    __syncthreads();
    if (t == 0) sh_sigma = sqrtf((red[0] + red[1] + red[2] + red[3]) / (float)D_MODEL);
    __syncthreads();
    const float sigma = sh_sigma;
    const float* row = enc + (size_t)b * N_FEAT;

    for (int p = 0; p < 2; p++) {
        const int k = p ? AUX_K : K_TOP;
        int m;
        if (p == 0) {
            m = N_FEAT;
        } else {
            int lm = 0;
            for (int f = t; f < N_FEAT; f += 256) lm += (activated[f] > DEAD_AFTER) ? 1 : 0;
            for (int off = 32; off > 0; off >>= 1) lm += __shfl_down(lm, off, 64);
            __syncthreads();
            if (t == 0) sh_m = 0;
            __syncthreads();
            if ((t & 63) == 0) atomicAdd(&sh_m, lm);
            __syncthreads();
            m = sh_m;
        }
        const bool allmode = (m <= CAP);
        float tcur = allmode ? -INFINITY : sigma * (p ? 2.0f : 2.4f);
        int cnt = 0;
        for (int attempt = 0; attempt < 16; attempt++) {
            __syncthreads();
            if (t == 0) sh_cnt = 0;
            __syncthreads();
            for (int f = t; f < N_FEAT; f += 256) {
                bool elig = (p == 0) || (activated[f] > DEAD_AFTER);
                if (!elig) continue;
                float v = row[f];
                if (v > tcur) {
                    int pos = atomicAdd(&sh_cnt, 1);
                    if (pos < CAP)
                        cand[pos] = ((unsigned long long)sortable(v) << 32)
                                  | (unsigned long long)(0xFFFFFFFFu - (unsigned)f);
                }
            }
            __syncthreads();
            cnt = sh_cnt;
            int need = min(k, m);
            if (allmode || (cnt >= need && cnt <= CAP)) break;
            if (cnt > CAP) tcur += 0.3f * sigma;   // overflow: raise threshold, rescan
            else           tcur -= 0.6f * sigma;   // too few: lower threshold, rescan
        }
        if (cnt > CAP) cnt = CAP;  // safety; unreachable for this data
        int n_sort = k;
        while (n_sort < cnt) n_sort <<= 1;
        for (int i = t; i < n_sort; i += 256)
            if (i >= cnt) cand[i] = 0ULL;
        __syncthreads();
        // bitonic ascending sort of cand[0..n_sort)
        for (int size = 2; size <= n_sort; size <<= 1) {
            for (int stride = size >> 1; stride > 0; stride >>= 1) {
                for (int i = t; i < n_sort; i += 256) {
                    int j = i ^ stride;
                    if (j > i) {
                        unsigned long long x0 = cand[i], x1 = cand[j];
                        bool up = ((i & size) == 0);
                        if ((x0 > x1) == up) { cand[i] = x1; cand[j] = x0; }
                    }
                }
                __syncthreads();
            }
        }
        const int need = min(k, cnt);
        int*   oidx = p ? aidx : tidx;
        float* ow   = p ? aw   : tw;
        for (int s = t; s < k; s += 256) {
            float w = 0.f; int fi = 0;
            if (s < need) {
                unsigned long long e = cand[n_sort - 1 - s];
                w  = unsortable((unsigned)(e >> 32));
                fi = (int)(0xFFFFFFFFu - (unsigned)(e & 0xFFFFFFFFull));
            }
            ow[(size_t)b * k + s]   = w;
            oidx[(size_t)b * k + s] = fi;
        }
        if (p == 1 && b == 0 && t == 0) scal[2] = (m > 0) ? 1.f : 0.f;
        __syncthreads();
    }
}

// ---------------------------------------------------------------- decode + losses
__global__ __launch_bounds__(256) void k_decode(
    const float* __restrict__ Wdec, const float* __restrict__ xn,
    const int* __restrict__ tidx, const float* __restrict__ tw,
    const int* __restrict__ aidx, const float* __restrict__ aw,
    const float* __restrict__ b_post, const float* __restrict__ avg_norm,
    const float* __restrict__ scal,
    float* __restrict__ y, float* __restrict__ loss, float* __restrict__ accum) {
    const int b = blockIdx.x;
    const int t = threadIdx.x;
    __shared__ float sw[K_TOP];   __shared__ int sidx[K_TOP];
    __shared__ float saw[AUX_K];  __shared__ int saidx[AUX_K];
    __shared__ float red1[4], red2[4], red3[4];
    if (t < K_TOP) { sw[t] = tw[(size_t)b * K_TOP + t]; sidx[t] = tidx[(size_t)b * K_TOP + t]; }
    else if (t < K_TOP + AUX_K) {
        int j = t - K_TOP;
        saw[j] = aw[(size_t)b * AUX_K + j]; saidx[j] = aidx[(size_t)b * AUX_K + j];
    }
    __syncthreads();
    const float inv = avg_norm[0] / sqrtf((float)D_MODEL);
    float rsum = 0.f, asum = 0.f, xsum = 0.f;
#pragma unroll
    for (int c = 0; c < 3; c++) {
        const int d = t + 256 * c;
        float acc = 0.f;
#pragma unroll 8
        for (int j = 0; j < K_TOP; j++)
            acc = fmaf(sw[j], Wdec[(size_t)sidx[j] * D_MODEL + d], acc);
        float yn = acc + b_post[d];
        float aacc = 0.f;
#pragma unroll 8
        for (int j = 0; j < AUX_K; j++)
            aacc = fmaf(saw[j], Wdec[(size_t)saidx[j] * D_MODEL + d], aacc);
        float xv = xn[(size_t)b * D_MODEL + d];
        float r = xv - yn;
        rsum += r * r;
        float ar = yn - xv - aacc;
        asum += ar * ar;
        xsum += xv * xv;
        y[(size_t)b * D_MODEL + d] = yn * inv;
    }
    for (int off = 32; off > 0; off >>= 1) {
        rsum += __shfl_down(rsum, off, 64);
        asum += __shfl_down(asum, off, 64);
        xsum += __shfl_down(xsum, off, 64);
    }
    if ((t & 63) == 0) { int w = t >> 6; red1[w] = rsum; red2[w] = asum; red3[w] = xsum; }
    __syncthreads();
    if (t == 0) {
        float R = red1[0] + red1[1] + red1[2] + red1[3];
        float A = red2[0] + red2[1] + red2[2] + red2[3];
        float X = red3[0] + red3[1] + red3[2] + red3[3];
        float dead_any = scal[2];
        loss[b] = R / (float)D_MODEL + AUX_COEFF * (dead_any > 0.f ? A / (float)D_MODEL : 0.f);
        atomicAdd(&accum[0], R);
        atomicAdd(&accum[1], X);
    }
}

// ---------------------------------------------------------------- fvu
__global__ void k_fin(const float* __restrict__ accum, float* __restrict__ fvu_out) {
    *fvu_out = accum[0] / accum[1];
}

extern "C" void kernel_launch(void* const* d_in, const int* in_sizes, int n_in,
                              void* d_out, int out_size, void* d_ws, size_t ws_size,
                              hipStream_t stream) {
    const float* x      = (const float*)d_in[0];
    const float* W_enc  = (const float*)d_in[1];
    const float* W_dec  = (const float*)d_in[2];
    const float* b_pre  = (const float*)d_in[3];
    const float* b_post = (const float*)d_in[4];
    const float* avg    = (const float*)d_in[5];
    const int*   act    = (const int*)d_in[6];

    float* ws     = (float*)d_ws;
    float* xn     = ws;                         // 1024*768
    float* enc_in = xn + BATCH * D_MODEL;       // 1024*768
    float* enc    = enc_in + BATCH * D_MODEL;   // 1024*32768
    float* tw     = enc + (size_t)BATCH * N_FEAT;      // 1024*64
    int*   tidx   = (int*)(tw + BATCH * K_TOP);        // 1024*64
    float* aw     = (float*)(tidx + BATCH * K_TOP);    // 1024*128
    int*   aidx   = (int*)(aw + BATCH * AUX_K);        // 1024*128
    float* scal   = (float*)(aidx + BATCH * AUX_K);    // [0]=num [1]=den [2]=dead_any

    float* y    = (float*)d_out;
    float* loss = y + (size_t)BATCH * D_MODEL;
    float* fvu  = loss + BATCH;

    k_prep<<<1024, 256, 0, stream>>>(x, b_pre, b_post, avg, xn, enc_in, scal);
    k_gemm<<<dim3(N_FEAT / 128, BATCH / 128), 256, 0, stream>>>(enc_in, W_enc, enc);
    k_topk<<<BATCH, 256, 0, stream>>>(enc, enc_in, act, tidx, tw, aidx, aw, scal);
    k_decode<<<BATCH, 256, 0, stream>>>(W_dec, xn, tidx, tw, aidx, aw, b_post, avg, scal,
                                        y, loss, scal);
    k_fin<<<1, 1, 0, stream>>>(scal, fvu);
}

// Round 2
// 724.925 us; speedup vs baseline: 1.3802x; 1.3802x over previous
//
#include <hip/hip_runtime.h>
#include <math.h>

#define D_MODEL    768
#define N_FEAT     32768
#define K_TOP      64
#define AUX_K      128
#define BATCH      1024
#define DEAD_AFTER 1000
#define AUX_COEFF  0.03125f
#define ROWCAP     1024

typedef unsigned short u16;
typedef unsigned long long u64;
typedef __attribute__((ext_vector_type(8))) short short8;
typedef __attribute__((ext_vector_type(4))) float f32x4;

__device__ __forceinline__ unsigned sortable(float f) {
    unsigned u = __float_as_uint(f);
    return u ^ ((unsigned)((int)u >> 31) | 0x80000000u);
}
__device__ __forceinline__ float unsortable(unsigned s) {
    unsigned u = (s & 0x80000000u) ? (s ^ 0x80000000u) : ~s;
    return __uint_as_float(u);
}
__device__ __forceinline__ u16 f2bf(float v) {          // RNE f32->bf16 (no NaN inputs here)
    unsigned u = __float_as_uint(v);
    unsigned r = u + 0x7FFFu + ((u >> 16) & 1u);
    return (u16)(r >> 16);
}
__device__ __forceinline__ float bf2f(u16 u) {
    return __uint_as_float(((unsigned)u) << 16);
}
__device__ __forceinline__ void gll16(const u16* g, u16* l) {
    __builtin_amdgcn_global_load_lds(
        (const __attribute__((address_space(1))) unsigned*)g,
        (__attribute__((address_space(3))) unsigned*)l, 16, 0, 0);
}

// ---------------------------------------------------------------- prep: xn, enc_in, A hi/lo, sigma
__global__ __launch_bounds__(256) void k_prep(
    const float* __restrict__ x, const float* __restrict__ b_pre,
    const float* __restrict__ b_post, const float* __restrict__ avg,
    float* __restrict__ xn, float* __restrict__ enc_in,
    u16* __restrict__ Ah, u16* __restrict__ Al, float* __restrict__ sigma) {
    const int b = blockIdx.x, t = threadIdx.x;
    __shared__ float red[4];
    const float s = sqrtf((float)D_MODEL) / avg[0];
    float ss = 0.f;
#pragma unroll
    for (int c = 0; c < 3; c++) {
        int d = t + 256 * c;
        size_t i = (size_t)b * D_MODEL + d;
        float v = x[i] * s;
        xn[i] = v;
        float e = v - b_post[d] + b_pre[d];
        enc_in[i] = e;
        u16 hi = f2bf(e);
        Ah[i] = hi;
        Al[i] = f2bf(e - bf2f(hi));
        ss += e * e;
    }
    for (int o = 32; o > 0; o >>= 1) ss += __shfl_down(ss, o, 64);
    if ((t & 63) == 0) red[t >> 6] = ss;
    __syncthreads();
    if (t == 0) sigma[b] = sqrtf((red[0] + red[1] + red[2] + red[3]) / (float)D_MODEL);
}

// ---------------------------------------------------------------- dead-feature bitmask
__global__ __launch_bounds__(256) void k_dead(
    const int* __restrict__ act, u64* __restrict__ dmask, float* __restrict__ scal) {
    int f = blockIdx.x * 256 + threadIdx.x;
    bool dead = act[f] > DEAD_AFTER;
    u64 m = __ballot(dead);
    if ((threadIdx.x & 63) == 0) {
        dmask[f >> 6] = m;
        if (m != 0ULL) scal[2] = 1.0f;   // benign race
    }
}

// ---------------------------------------------------------------- W_enc -> Bt hi/lo (transpose + bf16 split)
__global__ __launch_bounds__(256) void k_convB(
    const float* __restrict__ W, u16* __restrict__ Bh, u16* __restrict__ Bl) {
    __shared__ float tile[32][33];
    const int bx = blockIdx.x;            // n tile 0..1023
    const int by = blockIdx.y;            // k tile 0..23
    const int tx = threadIdx.x & 31, ty = threadIdx.x >> 5;  // ty 0..7
#pragma unroll
    for (int it = 0; it < 4; it++) {
        int k = by * 32 + ty + it * 8;
        int n = bx * 32 + tx;
        tile[ty + it * 8][tx] = W[(size_t)k * N_FEAT + n];
    }
    __syncthreads();
#pragma unroll
    for (int it = 0; it < 4; it++) {
        int n = bx * 32 + ty + it * 8;
        int k = by * 32 + tx;
        float v = tile[tx][ty + it * 8];
        u16 hi = f2bf(v);
        Bh[(size_t)n * D_MODEL + k] = hi;
        Bl[(size_t)n * D_MODEL + k] = f2bf(v - bf2f(hi));
    }
}

// ---------------------------------------------------------------- W_dec -> bf16
__global__ __launch_bounds__(256) void k_convDec(const float* __restrict__ W, u16* __restrict__ o) {
    size_t i = ((size_t)blockIdx.x * 256 + threadIdx.x) * 4;
    float4 v = *(const float4*)(W + i);
    ushort4 r;
    r.x = f2bf(v.x); r.y = f2bf(v.y); r.z = f2bf(v.z); r.w = f2bf(v.w);
    *(ushort4*)(o + i) = r;
}

// ---------------------------------------------------------------- bf16x3 MFMA GEMM + fused candidate scan
__global__ __launch_bounds__(256) void k_gemm(
    const u16* __restrict__ Ah, const u16* __restrict__ Al,
    const u16* __restrict__ Bh, const u16* __restrict__ Bl,
    const float* __restrict__ sigma, const u64* __restrict__ dmask,
    u64* __restrict__ cand0, int* __restrict__ cnt0,
    u64* __restrict__ cand1, int* __restrict__ cnt1) {
    __shared__ __align__(16) u16 lds[16384];   // 4 planes x 4096 ushort = 32 KB
    const int l  = blockIdx.x;
    const int nx = (l & 7) + ((l >> 6) << 3);  // XCD swizzle: 8 m-blocks of an n-strip co-XCD
    const int my = (l >> 3) & 7;
    const int t  = threadIdx.x;
    const int w  = t >> 6, lane = t & 63;
    const int wm = w >> 1, wn = w & 1;
    const int lane15 = lane & 15, quad = lane >> 4;

    const int srow_ = t & 127;
    const int skq   = t >> 7;
    const u16* pA0 = Ah + (size_t)(my * 128 + srow_) * D_MODEL + skq * 8;
    const u16* pA1 = Al + (size_t)(my * 128 + srow_) * D_MODEL + skq * 8;
    const u16* pB0 = Bh + (size_t)(nx * 128 + srow_) * D_MODEL + skq * 8;
    const u16* pB1 = Bl + (size_t)(nx * 128 + srow_) * D_MODEL + skq * 8;
    u16* lp = &lds[t * 8];

    f32x4 acc[4][4];
#pragma unroll
    for (int i = 0; i < 4; i++)
#pragma unroll
        for (int j = 0; j < 4; j++) acc[i][j] = (f32x4){0.f, 0.f, 0.f, 0.f};

    const int foff  = quad * 1024 + lane15 * 8;   // ushort units within a plane
    const int abase = wm * 512 + foff;
    const int bbase = wn * 512 + foff;

    for (int k0 = 0; k0 < D_MODEL; k0 += 32) {
        __syncthreads();
        gll16(pA0 + k0,      lp);
        gll16(pA0 + k0 + 16, lp + 2048);
        gll16(pA1 + k0,      lp + 4096);
        gll16(pA1 + k0 + 16, lp + 6144);
        gll16(pB0 + k0,      lp + 8192);
        gll16(pB0 + k0 + 16, lp + 10240);
        gll16(pB1 + k0,      lp + 12288);
        gll16(pB1 + k0 + 16, lp + 14336);
        __syncthreads();   // drains vmcnt -> staged data visible
        short8 ah[4], al4[4], bh[4], bl4[4];
#pragma unroll
        for (int i = 0; i < 4; i++) {
            ah[i]  = *(const short8*)&lds[abase + i * 128];
            al4[i] = *(const short8*)&lds[4096  + abase + i * 128];
            bh[i]  = *(const short8*)&lds[8192  + bbase + i * 128];
            bl4[i] = *(const short8*)&lds[12288 + bbase + i * 128];
        }
#pragma unroll
        for (int i = 0; i < 4; i++)
#pragma unroll
            for (int j = 0; j < 4; j++) {
                acc[i][j] = __builtin_amdgcn_mfma_f32_16x16x32_bf16(ah[i],  bh[j],  acc[i][j], 0, 0, 0);
                acc[i][j] = __builtin_amdgcn_mfma_f32_16x16x32_bf16(ah[i],  bl4[j], acc[i][j], 0, 0, 0);
                acc[i][j] = __builtin_amdgcn_mfma_f32_16x16x32_bf16(al4[i], bh[j],  acc[i][j], 0, 0, 0);
            }
    }
    // ---- epilogue: threshold scan, no C materialization
    __syncthreads();
    float* srow = (float*)lds;          // 128 floats
    u64*   sdw  = (u64*)&lds[256];      // 2 u64 at byte 512
    if (t < 128) srow[t] = sigma[my * 128 + t];
    if (t == 128) sdw[0] = dmask[nx * 2];
    if (t == 129) sdw[1] = dmask[nx * 2 + 1];
    __syncthreads();
#pragma unroll
    for (int i = 0; i < 4; i++)
#pragma unroll
        for (int j = 0; j < 4; j++)
#pragma unroll
            for (int r = 0; r < 4; r++) {
                int rl = wm * 64 + i * 16 + quad * 4 + r;   // C/D row = A side
                int cl = wn * 64 + j * 16 + lane15;         // C/D col = B side
                float v = acc[i][j][r];
                float sg = srow[rl];
                if (v > 2.0f * sg) {
                    int grow = my * 128 + rl;
                    unsigned gcol = (unsigned)(nx * 128 + cl);
                    u64 key = ((u64)sortable(v) << 32) | (u64)(0xFFFFFFFFu - gcol);
                    if (v > 2.4f * sg) {
                        int p = atomicAdd(&cnt0[grow], 1);
                        if (p < ROWCAP) cand0[(size_t)grow * ROWCAP + p] = key;
                    }
                    if ((sdw[cl >> 6] >> (cl & 63)) & 1ULL) {
                        int p = atomicAdd(&cnt1[grow], 1);
                        if (p < ROWCAP) cand1[(size_t)grow * ROWCAP + p] = key;
                    }
                }
            }
}

// ---------------------------------------------------------------- topk: sort candidates, exact-f32 rescue at rank-64
__device__ __forceinline__ void bitonic(u64* sbuf, int ns, int t) {
    for (int size = 2; size <= ns; size <<= 1) {
        for (int stride = size >> 1; stride > 0; stride >>= 1) {
            for (int i = t; i < ns; i += 256) {
                int j = i ^ stride;
                if (j > i) {
                    u64 x0 = sbuf[i], x1 = sbuf[j];
                    bool up = ((i & size) == 0);
                    if ((x0 > x1) == up) { sbuf[i] = x1; sbuf[j] = x0; }
                }
            }
            __syncthreads();
        }
    }
}

__global__ __launch_bounds__(256) void k_topk(
    const u64* __restrict__ cand0, const int* __restrict__ cnt0,
    const u64* __restrict__ cand1, const int* __restrict__ cnt1,
    const float* __restrict__ enc_in, const float* __restrict__ W_enc,
    const float* __restrict__ sigma,
    int* __restrict__ tidx, float* __restrict__ tw,
    int* __restrict__ aidx, float* __restrict__ aw) {
    const int b = blockIdx.x, t = threadIdx.x;
    __shared__ u64 sbuf[ROWCAP];
    __shared__ int rlist[64];
    __shared__ int sh_rcnt;
    __shared__ float red[4];

    // ---------- pass 0: top-64 over all features
    int cnt = min(cnt0[b], ROWCAP);
    int ns = 64; while (ns < cnt) ns <<= 1;
    for (int i = t; i < ns; i += 256) sbuf[i] = (i < cnt) ? cand0[(size_t)b * ROWCAP + i] : 0ULL;
    __syncthreads();
    bitonic(sbuf, ns, t);   // ascending; top values at the end
    // rescue: exact f32 dot for candidates within delta of the approx rank-64 value
    const float delta = 4e-4f * sigma[b];
    float v64 = (cnt >= K_TOP) ? unsortable((unsigned)(sbuf[ns - K_TOP] >> 32)) : 0.f;
    if (t == 0) sh_rcnt = 0;
    __syncthreads();
    if (cnt >= K_TOP) {
        for (int i = t; i < ns; i += 256) {
            float v = unsortable((unsigned)(sbuf[i] >> 32));  // pad entries -> NaN -> excluded
            if (fabsf(v - v64) <= delta) {
                int p = atomicAdd(&sh_rcnt, 1);
                if (p < 64) rlist[p] = i;
            }
        }
    }
    __syncthreads();
    int rc = min(sh_rcnt, 64);
    if (rc >= 2) {   // competition at the boundary: recompute exactly
        for (int r = 0; r < rc; r++) {
            int ip = rlist[r];
            u64 e = sbuf[ip];
            unsigned fi = 0xFFFFFFFFu - (unsigned)(e & 0xFFFFFFFFull);
            float ss = 0.f;
            for (int d = t; d < D_MODEL; d += 256)
                ss += enc_in[(size_t)b * D_MODEL + d] * W_enc[(size_t)d * N_FEAT + fi];
            for (int o = 32; o > 0; o >>= 1) ss += __shfl_down(ss, o, 64);
            if ((t & 63) == 0) red[t >> 6] = ss;
            __syncthreads();
            if (t == 0) {
                float ex = red[0] + red[1] + red[2] + red[3];
                sbuf[ip] = ((u64)sortable(ex) << 32) | (e & 0xFFFFFFFFull);
            }
            __syncthreads();
        }
        bitonic(sbuf, ns, t);
    }
    if (t < K_TOP) {
        float wv = 0.f; int fi = 0;
        if (t < cnt) {
            u64 e = sbuf[ns - 1 - t];
            wv = unsortable((unsigned)(e >> 32));
            fi = (int)(0xFFFFFFFFu - (unsigned)(e & 0xFFFFFFFFull));
        }
        tw[(size_t)b * K_TOP + t] = wv;
        tidx[(size_t)b * K_TOP + t] = fi;
    }
    __syncthreads();

    // ---------- pass 1: aux top-128 over dead features
    cnt = min(cnt1[b], ROWCAP);
    ns = AUX_K; while (ns < cnt) ns <<= 1;
    for (int i = t; i < ns; i += 256) sbuf[i] = (i < cnt) ? cand1[(size_t)b * ROWCAP + i] : 0ULL;
    __syncthreads();
    bitonic(sbuf, ns, t);
    if (t < AUX_K) {
        float wv = 0.f; int fi = 0;
        if (t < cnt) {
            u64 e = sbuf[ns - 1 - t];
            wv = unsortable((unsigned)(e >> 32));
            fi = (int)(0xFFFFFFFFu - (unsigned)(e & 0xFFFFFFFFull));
        }
        aw[(size_t)b * AUX_K + t] = wv;
        aidx[(size_t)b * AUX_K + t] = fi;
    }
}

// ---------------------------------------------------------------- decode (bf16 W_dec) + losses
__global__ __launch_bounds__(256) void k_decode(
    const u16* __restrict__ Wd, const float* __restrict__ xn,
    const int* __restrict__ tidx, const float* __restrict__ tw,
    const int* __restrict__ aidx, const float* __restrict__ aw,
    const float* __restrict__ b_post, const float* __restrict__ avg,
    float* __restrict__ scal,
    float* __restrict__ y, float* __restrict__ loss) {
    const int b = blockIdx.x, t = threadIdx.x;
    __shared__ float sw[K_TOP];   __shared__ int sidx[K_TOP];
    __shared__ float saw[AUX_K];  __shared__ int saidx[AUX_K];
    __shared__ float red1[4], red2[4], red3[4];
    if (t < K_TOP) { sw[t] = tw[(size_t)b * K_TOP + t]; sidx[t] = tidx[(size_t)b * K_TOP + t]; }
    else if (t < K_TOP + AUX_K) {
        int j = t - K_TOP;
        saw[j] = aw[(size_t)b * AUX_K + j]; saidx[j] = aidx[(size_t)b * AUX_K + j];
    }
    __syncthreads();
    const float inv = avg[0] / sqrtf((float)D_MODEL);
    float rsum = 0.f, asum = 0.f, xsum = 0.f;
#pragma unroll
    for (int c = 0; c < 3; c++) {
        const int d = t + 256 * c;
        float acc = 0.f;
#pragma unroll 8
        for (int j = 0; j < K_TOP; j++)
            acc = fmaf(sw[j], bf2f(Wd[(size_t)sidx[j] * D_MODEL + d]), acc);
        float yn = acc + b_post[d];
        float aacc = 0.f;
#pragma unroll 8
        for (int j = 0; j < AUX_K; j++)
            aacc = fmaf(saw[j], bf2f(Wd[(size_t)saidx[j] * D_MODEL + d]), aacc);
        float xv = xn[(size_t)b * D_MODEL + d];
        float r = xv - yn;
        rsum += r * r;
        float ar = yn - xv - aacc;
        asum += ar * ar;
        xsum += xv * xv;
        y[(size_t)b * D_MODEL + d] = yn * inv;
    }
    for (int o = 32; o > 0; o >>= 1) {
        rsum += __shfl_down(rsum, o, 64);
        asum += __shfl_down(asum, o, 64);
        xsum += __shfl_down(xsum, o, 64);
    }
    if ((t & 63) == 0) { int w = t >> 6; red1[w] = rsum; red2[w] = asum; red3[w] = xsum; }
    __syncthreads();
    if (t == 0) {
        float R = red1[0] + red1[1] + red1[2] + red1[3];
        float A = red2[0] + red2[1] + red2[2] + red2[3];
        float X = red3[0] + red3[1] + red3[2] + red3[3];
        loss[b] = R / (float)D_MODEL + AUX_COEFF * (scal[2] > 0.f ? A / (float)D_MODEL : 0.f);
        atomicAdd(&scal[0], R);
        atomicAdd(&scal[1], X);
    }
}

__global__ void k_fin(const float* __restrict__ scal, float* __restrict__ fvu_out) {
    *fvu_out = scal[0] / scal[1];
}

// ---------------------------------------------------------------- launch
extern "C" void kernel_launch(void* const* d_in, const int* in_sizes, int n_in,
                              void* d_out, int out_size, void* d_ws, size_t ws_size,
                              hipStream_t stream) {
    const float* x      = (const float*)d_in[0];
    const float* W_enc  = (const float*)d_in[1];
    const float* W_dec  = (const float*)d_in[2];
    const float* b_pre  = (const float*)d_in[3];
    const float* b_post = (const float*)d_in[4];
    const float* avg    = (const float*)d_in[5];
    const int*   act    = (const int*)d_in[6];

    char* base = (char*)d_ws;
    // byte offsets (total ~122.5 MB; Wd_bf reuses the Bt_hi region after the GEMM)
    const size_t OFF_XN    = 0;
    const size_t OFF_ENCIN = 3145728;
    const size_t OFF_SIGMA = 6291456;
    const size_t OFF_AH    = 6295552;
    const size_t OFF_AL    = 7868416;
    const size_t OFF_CNT0  = 9441280;
    const size_t OFF_CNT1  = 9445376;
    const size_t OFF_DMASK = 9449472;
    const size_t OFF_SCAL  = 9453568;
    const size_t OFF_TW    = 9453824;
    const size_t OFF_TIDX  = 9715968;
    const size_t OFF_AW    = 9978112;
    const size_t OFF_AIDX  = 10502400;
    const size_t OFF_CAND0 = 11026688;
    const size_t OFF_CAND1 = 19415296;
    const size_t OFF_BTH   = 27803904;
    const size_t OFF_BTL   = 78135552;

    float* xn     = (float*)(base + OFF_XN);
    float* enc_in = (float*)(base + OFF_ENCIN);
    float* sigma  = (float*)(base + OFF_SIGMA);
    u16*   Ah     = (u16*)(base + OFF_AH);
    u16*   Al     = (u16*)(base + OFF_AL);
    int*   cnt0   = (int*)(base + OFF_CNT0);
    int*   cnt1   = (int*)(base + OFF_CNT1);
    u64*   dmask  = (u64*)(base + OFF_DMASK);
    float* scal   = (float*)(base + OFF_SCAL);
    float* tw     = (float*)(base + OFF_TW);
    int*   tidx   = (int*)(base + OFF_TIDX);
    float* aw     = (float*)(base + OFF_AW);
    int*   aidx   = (int*)(base + OFF_AIDX);
    u64*   cand0  = (u64*)(base + OFF_CAND0);
    u64*   cand1  = (u64*)(base + OFF_CAND1);
    u16*   Bth    = (u16*)(base + OFF_BTH);
    u16*   Btl    = (u16*)(base + OFF_BTL);
    u16*   Wdb    = (u16*)(base + OFF_BTH);   // reuse after gemm

    float* y    = (float*)d_out;
    float* loss = y + (size_t)BATCH * D_MODEL;
    float* fvu  = loss + BATCH;

    hipMemsetAsync(base + OFF_CNT0, 0, 12544, stream);  // cnt0+cnt1+dmask+scal

    k_prep<<<BATCH, 256, 0, stream>>>(x, b_pre, b_post, avg, xn, enc_in, Ah, Al, sigma);
    k_dead<<<N_FEAT / 256, 256, 0, stream>>>(act, dmask, scal);
    k_convB<<<dim3(N_FEAT / 32, D_MODEL / 32), 256, 0, stream>>>(W_enc, Bth, Btl);
    k_gemm<<<(N_FEAT / 128) * (BATCH / 128), 256, 0, stream>>>(
        Ah, Al, Bth, Btl, sigma, dmask, cand0, cnt0, cand1, cnt1);
    k_convDec<<<(N_FEAT * D_MODEL) / 1024, 256, 0, stream>>>(W_dec, Wdb);
    k_topk<<<BATCH, 256, 0, stream>>>(cand0, cnt0, cand1, cnt1, enc_in, W_enc, sigma,
                                      tidx, tw, aidx, aw);
    k_decode<<<BATCH, 256, 0, stream>>>(Wdb, xn, tidx, tw, aidx, aw, b_post, avg, scal, y, loss);
    k_fin<<<1, 1, 0, stream>>>(scal, fvu);
}

// Round 3
// 704.347 us; speedup vs baseline: 1.4205x; 1.0292x over previous
//
#include <hip/hip_runtime.h>
#include <math.h>

#define D_MODEL    768
#define N_FEAT     32768
#define K_TOP      64
#define AUX_K      128
#define BATCH      1024
#define DEAD_AFTER 1000
#define AUX_COEFF  0.03125f
#define ROWCAP     1024

typedef unsigned short u16;
typedef unsigned long long u64;
typedef __attribute__((ext_vector_type(8))) short short8;
typedef __attribute__((ext_vector_type(4))) float f32x4;

__device__ __forceinline__ unsigned sortable(float f) {
    unsigned u = __float_as_uint(f);
    return u ^ ((unsigned)((int)u >> 31) | 0x80000000u);
}
__device__ __forceinline__ float unsortable(unsigned s) {
    unsigned u = (s & 0x80000000u) ? (s ^ 0x80000000u) : ~s;
    return __uint_as_float(u);
}
__device__ __forceinline__ u16 f2bf(float v) {          // RNE f32->bf16 (no NaN inputs here)
    unsigned u = __float_as_uint(v);
    unsigned r = u + 0x7FFFu + ((u >> 16) & 1u);
    return (u16)(r >> 16);
}
__device__ __forceinline__ float bf2f(u16 u) {
    return __uint_as_float(((unsigned)u) << 16);
}
__device__ __forceinline__ void gll16(const u16* g, u16* l) {
    __builtin_amdgcn_global_load_lds(
        (const __attribute__((address_space(1))) unsigned*)g,
        (__attribute__((address_space(3))) unsigned*)l, 16, 0, 0);
}

// ---------------------------------------------------------------- prep: xn, enc_in, A hi/lo, sigma
__global__ __launch_bounds__(256) void k_prep(
    const float* __restrict__ x, const float* __restrict__ b_pre,
    const float* __restrict__ b_post, const float* __restrict__ avg,
    float* __restrict__ xn, float* __restrict__ enc_in,
    u16* __restrict__ Ah, u16* __restrict__ Al, float* __restrict__ sigma) {
    const int b = blockIdx.x, t = threadIdx.x;
    __shared__ float red[4];
    const float s = sqrtf((float)D_MODEL) / avg[0];
    float ss = 0.f;
#pragma unroll
    for (int c = 0; c < 3; c++) {
        int d = t + 256 * c;
        size_t i = (size_t)b * D_MODEL + d;
        float v = x[i] * s;
        xn[i] = v;
        float e = v - b_post[d] + b_pre[d];
        enc_in[i] = e;
        u16 hi = f2bf(e);
        Ah[i] = hi;
        Al[i] = f2bf(e - bf2f(hi));
        ss += e * e;
    }
    for (int o = 32; o > 0; o >>= 1) ss += __shfl_down(ss, o, 64);
    if ((t & 63) == 0) red[t >> 6] = ss;
    __syncthreads();
    if (t == 0) sigma[b] = sqrtf((red[0] + red[1] + red[2] + red[3]) / (float)D_MODEL);
}

// ---------------------------------------------------------------- dead-feature bitmask
__global__ __launch_bounds__(256) void k_dead(
    const int* __restrict__ act, u64* __restrict__ dmask, float* __restrict__ scal) {
    int f = blockIdx.x * 256 + threadIdx.x;
    bool dead = act[f] > DEAD_AFTER;
    u64 m = __ballot(dead);
    if ((threadIdx.x & 63) == 0) {
        dmask[f >> 6] = m;
        if (m != 0ULL) scal[2] = 1.0f;   // benign race
    }
}

// ---------------------------------------------------------------- W_enc -> Bt hi/lo (transpose + bf16 split)
// 64x64 tiles: coalesced f32 reads, LDS transpose (stride 65: conflict-free), 16B short8 writes.
__global__ __launch_bounds__(256) void k_convB(
    const float* __restrict__ W, u16* __restrict__ Bh, u16* __restrict__ Bl) {
    __shared__ float tile[64][65];
    const int bx = blockIdx.x;            // n tile 0..511
    const int by = blockIdx.y;            // k tile 0..11
    const int tx = threadIdx.x & 63;      // n within tile
    const int ty = threadIdx.x >> 6;      // 0..3
#pragma unroll
    for (int it = 0; it < 16; it++) {
        int k = ty + it * 4;
        tile[k][tx] = W[(size_t)(by * 64 + k) * N_FEAT + bx * 64 + tx];
    }
    __syncthreads();
    const int n  = threadIdx.x >> 2;      // 0..63
    const int kg = threadIdx.x & 3;       // 0..3 (16 k's each)
    u16 h[16], lo[16];
#pragma unroll
    for (int i = 0; i < 16; i++) {
        float v = tile[kg * 16 + i][n];
        h[i]  = f2bf(v);
        lo[i] = f2bf(v - bf2f(h[i]));
    }
    size_t off = (size_t)(bx * 64 + n) * D_MODEL + by * 64 + kg * 16;
    *(short8*)&Bh[off]     = *(short8*)&h[0];
    *(short8*)&Bh[off + 8] = *(short8*)&h[8];
    *(short8*)&Bl[off]     = *(short8*)&lo[0];
    *(short8*)&Bl[off + 8] = *(short8*)&lo[8];
}

// ---------------------------------------------------------------- bf16x3 MFMA GEMM + fused candidate scan
// Double-buffered LDS: prefetch of step k+1 issued right after the barrier,
// overlapping global_load_lds latency with ds_read+MFMA of step k.
__global__ __launch_bounds__(256) void k_gemm(
    const u16* __restrict__ Ah, const u16* __restrict__ Al,
    const u16* __restrict__ Bh, const u16* __restrict__ Bl,
    const float* __restrict__ sigma, const u64* __restrict__ dmask,
    u64* __restrict__ cand0, int* __restrict__ cnt0,
    u64* __restrict__ cand1, int* __restrict__ cnt1) {
    __shared__ __align__(16) u16 lds[32768];   // 2 bufs x 4 planes x 4096 ushort = 64 KB
    const int l  = blockIdx.x;
    const int nx = (l & 7) + ((l >> 6) << 3);  // XCD swizzle: 8 m-blocks of an n-strip co-XCD
    const int my = (l >> 3) & 7;
    const int t  = threadIdx.x;
    const int w  = t >> 6, lane = t & 63;
    const int wm = w >> 1, wn = w & 1;
    const int lane15 = lane & 15, quad = lane >> 4;

    const int srow_ = t & 127;
    const int skq   = t >> 7;
    const u16* pA0 = Ah + (size_t)(my * 128 + srow_) * D_MODEL + skq * 8;
    const u16* pA1 = Al + (size_t)(my * 128 + srow_) * D_MODEL + skq * 8;
    const u16* pB0 = Bh + (size_t)(nx * 128 + srow_) * D_MODEL + skq * 8;
    const u16* pB1 = Bl + (size_t)(nx * 128 + srow_) * D_MODEL + skq * 8;
    u16* lp = &lds[t * 8];

    auto stage = [&](int k0, int buf) {
        u16* d = lp + buf * 16384;
        gll16(pA0 + k0,      d);
        gll16(pA0 + k0 + 16, d + 2048);
        gll16(pA1 + k0,      d + 4096);
        gll16(pA1 + k0 + 16, d + 6144);
        gll16(pB0 + k0,      d + 8192);
        gll16(pB0 + k0 + 16, d + 10240);
        gll16(pB1 + k0,      d + 12288);
        gll16(pB1 + k0 + 16, d + 14336);
    };

    f32x4 acc[4][4];
#pragma unroll
    for (int i = 0; i < 4; i++)
#pragma unroll
        for (int j = 0; j < 4; j++) acc[i][j] = (f32x4){0.f, 0.f, 0.f, 0.f};

    const int foff  = quad * 1024 + lane15 * 8;   // ushort units within a plane
    const int abase = wm * 512 + foff;
    const int bbase = wn * 512 + foff;

    stage(0, 0);
    int cur = 0;
    for (int ks = 0; ks < D_MODEL / 32; ks++) {
        __syncthreads();             // drains vmcnt(0): buf[cur] staged; prior ds_reads done
        if (ks + 1 < D_MODEL / 32) stage((ks + 1) * 32, cur ^ 1);   // async prefetch
        const u16* L = lds + cur * 16384;
        short8 ah[4], al4[4], bh4[4], bl4[4];
#pragma unroll
        for (int i = 0; i < 4; i++) {
            ah[i]  = *(const short8*)&L[abase + i * 128];
            al4[i] = *(const short8*)&L[4096  + abase + i * 128];
            bh4[i] = *(const short8*)&L[8192  + bbase + i * 128];
            bl4[i] = *(const short8*)&L[12288 + bbase + i * 128];
        }
#pragma unroll
        for (int i = 0; i < 4; i++)
#pragma unroll
            for (int j = 0; j < 4; j++) {
                acc[i][j] = __builtin_amdgcn_mfma_f32_16x16x32_bf16(ah[i],  bh4[j], acc[i][j], 0, 0, 0);
                acc[i][j] = __builtin_amdgcn_mfma_f32_16x16x32_bf16(ah[i],  bl4[j], acc[i][j], 0, 0, 0);
                acc[i][j] = __builtin_amdgcn_mfma_f32_16x16x32_bf16(al4[i], bh4[j], acc[i][j], 0, 0, 0);
            }
        cur ^= 1;
    }
    // ---- epilogue: threshold scan, no C materialization
    __syncthreads();
    float* srow = (float*)lds;          // 128 floats
    u64*   sdw  = (u64*)&lds[256];      // 2 u64 at byte 512
    if (t < 128) srow[t] = sigma[my * 128 + t];
    if (t == 128) sdw[0] = dmask[nx * 2];
    if (t == 129) sdw[1] = dmask[nx * 2 + 1];
    __syncthreads();
#pragma unroll
    for (int i = 0; i < 4; i++)
#pragma unroll
        for (int j = 0; j < 4; j++)
#pragma unroll
            for (int r = 0; r < 4; r++) {
                int rl = wm * 64 + i * 16 + quad * 4 + r;   // C/D row = A side
                int cl = wn * 64 + j * 16 + lane15;         // C/D col = B side
                float v = acc[i][j][r];
                float sg = srow[rl];
                if (v > 2.0f * sg) {
                    int grow = my * 128 + rl;
                    unsigned gcol = (unsigned)(nx * 128 + cl);
                    u64 key = ((u64)sortable(v) << 32) | (u64)(0xFFFFFFFFu - gcol);
                    if (v > 2.4f * sg) {
                        int p = atomicAdd(&cnt0[grow], 1);
                        if (p < ROWCAP) cand0[(size_t)grow * ROWCAP + p] = key;
                    }
                    if ((sdw[cl >> 6] >> (cl & 63)) & 1ULL) {
                        int p = atomicAdd(&cnt1[grow], 1);
                        if (p < ROWCAP) cand1[(size_t)grow * ROWCAP + p] = key;
                    }
                }
            }
}

// ---------------------------------------------------------------- topk: sort candidates, exact-f32 rescue at rank-64
__device__ __forceinline__ void bitonic(u64* sbuf, int ns, int t) {
    for (int size = 2; size <= ns; size <<= 1) {
        for (int stride = size >> 1; stride > 0; stride >>= 1) {
            for (int i = t; i < ns; i += 256) {
                int j = i ^ stride;
                if (j > i) {
                    u64 x0 = sbuf[i], x1 = sbuf[j];
                    bool up = ((i & size) == 0);
                    if ((x0 > x1) == up) { sbuf[i] = x1; sbuf[j] = x0; }
                }
            }
            __syncthreads();
        }
    }
}

__global__ __launch_bounds__(256) void k_topk(
    const u64* __restrict__ cand0, const int* __restrict__ cnt0,
    const u64* __restrict__ cand1, const int* __restrict__ cnt1,
    const float* __restrict__ enc_in, const float* __restrict__ W_enc,
    const float* __restrict__ sigma,
    int* __restrict__ tidx, float* __restrict__ tw,
    int* __restrict__ aidx, float* __restrict__ aw) {
    const int b = blockIdx.x, t = threadIdx.x;
    __shared__ u64 sbuf[ROWCAP];
    __shared__ int rlist[64];
    __shared__ int sh_rcnt;
    __shared__ float red[4];

    // ---------- pass 0: top-64 over all features
    int cnt = min(cnt0[b], ROWCAP);
    int ns = 64; while (ns < cnt) ns <<= 1;
    for (int i = t; i < ns; i += 256) sbuf[i] = (i < cnt) ? cand0[(size_t)b * ROWCAP + i] : 0ULL;
    __syncthreads();
    bitonic(sbuf, ns, t);   // ascending; top values at the end
    // rescue: exact f32 dot for candidates within delta of the approx rank-64 value
    const float delta = 4e-4f * sigma[b];
    float v64 = (cnt >= K_TOP) ? unsortable((unsigned)(sbuf[ns - K_TOP] >> 32)) : 0.f;
    if (t == 0) sh_rcnt = 0;
    __syncthreads();
    if (cnt >= K_TOP) {
        for (int i = t; i < ns; i += 256) {
            float v = unsortable((unsigned)(sbuf[i] >> 32));  // pad entries -> NaN -> excluded
            if (fabsf(v - v64) <= delta) {
                int p = atomicAdd(&sh_rcnt, 1);
                if (p < 64) rlist[p] = i;
            }
        }
    }
    __syncthreads();
    int rc = min(sh_rcnt, 64);
    if (rc >= 2) {   // competition at the boundary: recompute exactly
        for (int r = 0; r < rc; r++) {
            int ip = rlist[r];
            u64 e = sbuf[ip];
            unsigned fi = 0xFFFFFFFFu - (unsigned)(e & 0xFFFFFFFFull);
            float ss = 0.f;
            for (int d = t; d < D_MODEL; d += 256)
                ss += enc_in[(size_t)b * D_MODEL + d] * W_enc[(size_t)d * N_FEAT + fi];
            for (int o = 32; o > 0; o >>= 1) ss += __shfl_down(ss, o, 64);
            if ((t & 63) == 0) red[t >> 6] = ss;
            __syncthreads();
            if (t == 0) {
                float ex = red[0] + red[1] + red[2] + red[3];
                sbuf[ip] = ((u64)sortable(ex) << 32) | (e & 0xFFFFFFFFull);
            }
            __syncthreads();
        }
        bitonic(sbuf, ns, t);
    }
    if (t < K_TOP) {
        float wv = 0.f; int fi = 0;
        if (t < cnt) {
            u64 e = sbuf[ns - 1 - t];
            wv = unsortable((unsigned)(e >> 32));
            fi = (int)(0xFFFFFFFFu - (unsigned)(e & 0xFFFFFFFFull));
        }
        tw[(size_t)b * K_TOP + t] = wv;
        tidx[(size_t)b * K_TOP + t] = fi;
    }
    __syncthreads();

    // ---------- pass 1: aux top-128 over dead features
    cnt = min(cnt1[b], ROWCAP);
    ns = AUX_K; while (ns < cnt) ns <<= 1;
    for (int i = t; i < ns; i += 256) sbuf[i] = (i < cnt) ? cand1[(size_t)b * ROWCAP + i] : 0ULL;
    __syncthreads();
    bitonic(sbuf, ns, t);
    if (t < AUX_K) {
        float wv = 0.f; int fi = 0;
        if (t < cnt) {
            u64 e = sbuf[ns - 1 - t];
            wv = unsortable((unsigned)(e >> 32));
            fi = (int)(0xFFFFFFFFu - (unsigned)(e & 0xFFFFFFFFull));
        }
        aw[(size_t)b * AUX_K + t] = wv;
        aidx[(size_t)b * AUX_K + t] = fi;
    }
}

// ---------------------------------------------------------------- decode (f32 W_dec direct) + losses
__global__ __launch_bounds__(256) void k_decode(
    const float* __restrict__ Wd, const float* __restrict__ xn,
    const int* __restrict__ tidx, const float* __restrict__ tw,
    const int* __restrict__ aidx, const float* __restrict__ aw,
    const float* __restrict__ b_post, const float* __restrict__ avg,
    float* __restrict__ scal,
    float* __restrict__ y, float* __restrict__ loss) {
    const int b = blockIdx.x, t = threadIdx.x;
    __shared__ float sw[K_TOP];   __shared__ int sidx[K_TOP];
    __shared__ float saw[AUX_K];  __shared__ int saidx[AUX_K];
    __shared__ float red1[4], red2[4], red3[4];
    if (t < K_TOP) { sw[t] = tw[(size_t)b * K_TOP + t]; sidx[t] = tidx[(size_t)b * K_TOP + t]; }
    else if (t < K_TOP + AUX_K) {
        int j = t - K_TOP;
        saw[j] = aw[(size_t)b * AUX_K + j]; saidx[j] = aidx[(size_t)b * AUX_K + j];
    }
    __syncthreads();
    const float inv = avg[0] / sqrtf((float)D_MODEL);
    float rsum = 0.f, asum = 0.f, xsum = 0.f;
#pragma unroll
    for (int c = 0; c < 3; c++) {
        const int d = t + 256 * c;
        float acc = 0.f;
#pragma unroll 8
        for (int j = 0; j < K_TOP; j++)
            acc = fmaf(sw[j], Wd[(size_t)sidx[j] * D_MODEL + d], acc);
        float yn = acc + b_post[d];
        float aacc = 0.f;
#pragma unroll 8
        for (int j = 0; j < AUX_K; j++)
            aacc = fmaf(saw[j], Wd[(size_t)saidx[j] * D_MODEL + d], aacc);
        float xv = xn[(size_t)b * D_MODEL + d];
        float r = xv - yn;
        rsum += r * r;
        float ar = yn - xv - aacc;
        asum += ar * ar;
        xsum += xv * xv;
        y[(size_t)b * D_MODEL + d] = yn * inv;
    }
    for (int o = 32; o > 0; o >>= 1) {
        rsum += __shfl_down(rsum, o, 64);
        asum += __shfl_down(asum, o, 64);
        xsum += __shfl_down(xsum, o, 64);
    }
    if ((t & 63) == 0) { int w = t >> 6; red1[w] = rsum; red2[w] = asum; red3[w] = xsum; }
    __syncthreads();
    if (t == 0) {
        float R = red1[0] + red1[1] + red1[2] + red1[3];
        float A = red2[0] + red2[1] + red2[2] + red2[3];
        float X = red3[0] + red3[1] + red3[2] + red3[3];
        loss[b] = R / (float)D_MODEL + AUX_COEFF * (scal[2] > 0.f ? A / (float)D_MODEL : 0.f);
        atomicAdd(&scal[0], R);
        atomicAdd(&scal[1], X);
    }
}

__global__ void k_fin(const float* __restrict__ scal, float* __restrict__ fvu_out) {
    *fvu_out = scal[0] / scal[1];
}

// ---------------------------------------------------------------- launch
extern "C" void kernel_launch(void* const* d_in, const int* in_sizes, int n_in,
                              void* d_out, int out_size, void* d_ws, size_t ws_size,
                              hipStream_t stream) {
    const float* x      = (const float*)d_in[0];
    const float* W_enc  = (const float*)d_in[1];
    const float* W_dec  = (const float*)d_in[2];
    const float* b_pre  = (const float*)d_in[3];
    const float* b_post = (const float*)d_in[4];
    const float* avg    = (const float*)d_in[5];
    const int*   act    = (const int*)d_in[6];

    char* base = (char*)d_ws;
    const size_t OFF_XN    = 0;
    const size_t OFF_ENCIN = 3145728;
    const size_t OFF_SIGMA = 6291456;
    const size_t OFF_AH    = 6295552;
    const size_t OFF_AL    = 7868416;
    const size_t OFF_CNT0  = 9441280;
    const size_t OFF_CNT1  = 9445376;
    const size_t OFF_DMASK = 9449472;
    const size_t OFF_SCAL  = 9453568;
    const size_t OFF_TW    = 9453824;
    const size_t OFF_TIDX  = 9715968;
    const size_t OFF_AW    = 9978112;
    const size_t OFF_AIDX  = 10502400;
    const size_t OFF_CAND0 = 11026688;
    const size_t OFF_CAND1 = 19415296;
    const size_t OFF_BTH   = 27803904;
    const size_t OFF_BTL   = 78135552;

    float* xn     = (float*)(base + OFF_XN);
    float* enc_in = (float*)(base + OFF_ENCIN);
    float* sigma  = (float*)(base + OFF_SIGMA);
    u16*   Ah     = (u16*)(base + OFF_AH);
    u16*   Al     = (u16*)(base + OFF_AL);
    int*   cnt0   = (int*)(base + OFF_CNT0);
    int*   cnt1   = (int*)(base + OFF_CNT1);
    u64*   dmask  = (u64*)(base + OFF_DMASK);
    float* scal   = (float*)(base + OFF_SCAL);
    float* tw     = (float*)(base + OFF_TW);
    int*   tidx   = (int*)(base + OFF_TIDX);
    float* aw     = (float*)(base + OFF_AW);
    int*   aidx   = (int*)(base + OFF_AIDX);
    u64*   cand0  = (u64*)(base + OFF_CAND0);
    u64*   cand1  = (u64*)(base + OFF_CAND1);
    u16*   Bth    = (u16*)(base + OFF_BTH);
    u16*   Btl    = (u16*)(base + OFF_BTL);

    float* y    = (float*)d_out;
    float* loss = y + (size_t)BATCH * D_MODEL;
    float* fvu  = loss + BATCH;

    hipMemsetAsync(base + OFF_CNT0, 0, 12544, stream);  // cnt0+cnt1+dmask+scal

    k_prep<<<BATCH, 256, 0, stream>>>(x, b_pre, b_post, avg, xn, enc_in, Ah, Al, sigma);
    k_dead<<<N_FEAT / 256, 256, 0, stream>>>(act, dmask, scal);
    k_convB<<<dim3(N_FEAT / 64, D_MODEL / 64), 256, 0, stream>>>(W_enc, Bth, Btl);
    k_gemm<<<(N_FEAT / 128) * (BATCH / 128), 256, 0, stream>>>(
        Ah, Al, Bth, Btl, sigma, dmask, cand0, cnt0, cand1, cnt1);
    k_topk<<<BATCH, 256, 0, stream>>>(cand0, cnt0, cand1, cnt1, enc_in, W_enc, sigma,
                                      tidx, tw, aidx, aw);
    k_decode<<<BATCH, 256, 0, stream>>>(W_dec, xn, tidx, tw, aidx, aw, b_post, avg, scal, y, loss);
    k_fin<<<1, 1, 0, stream>>>(scal, fvu);
}

// Round 4
// 637.911 us; speedup vs baseline: 1.5684x; 1.1041x over previous
//
#include <hip/hip_runtime.h>
#include <math.h>

#define D_MODEL    768
#define N_FEAT     32768
#define K_TOP      64
#define AUX_K      128
#define BATCH      1024
#define DEAD_AFTER 1000
#define AUX_COEFF  0.03125f
#define ROWCAP     1024
#define RESCUE_CAP 96

typedef unsigned short u16;
typedef unsigned long long u64;
typedef __attribute__((ext_vector_type(8))) short short8;
typedef __attribute__((ext_vector_type(4))) float f32x4;

__device__ __forceinline__ unsigned sortable(float f) {
    unsigned u = __float_as_uint(f);
    return u ^ ((unsigned)((int)u >> 31) | 0x80000000u);
}
__device__ __forceinline__ float unsortable(unsigned s) {
    unsigned u = (s & 0x80000000u) ? (s ^ 0x80000000u) : ~s;
    return __uint_as_float(u);
}
__device__ __forceinline__ u16 f2bf(float v) {          // RNE f32->bf16
    unsigned u = __float_as_uint(v);
    unsigned r = u + 0x7FFFu + ((u >> 16) & 1u);
    return (u16)(r >> 16);
}
__device__ __forceinline__ float bf2f(u16 u) {
    return __uint_as_float(((unsigned)u) << 16);
}
__device__ __forceinline__ void gll16(const u16* g, u16* l) {
    __builtin_amdgcn_global_load_lds(
        (const __attribute__((address_space(1))) unsigned*)g,
        (__attribute__((address_space(3))) unsigned*)l, 16, 0, 0);
}

// ---------------------------------------------------------------- prep: xn, enc_in, Ah, sigma
__global__ __launch_bounds__(256) void k_prep(
    const float* __restrict__ x, const float* __restrict__ b_pre,
    const float* __restrict__ b_post, const float* __restrict__ avg,
    float* __restrict__ xn, float* __restrict__ enc_in,
    u16* __restrict__ Ah, float* __restrict__ sigma) {
    const int b = blockIdx.x, t = threadIdx.x;
    __shared__ float red[4];
    const float s = sqrtf((float)D_MODEL) / avg[0];
    float ss = 0.f;
#pragma unroll
    for (int c = 0; c < 3; c++) {
        int d = t + 256 * c;
        size_t i = (size_t)b * D_MODEL + d;
        float v = x[i] * s;
        xn[i] = v;
        float e = v - b_post[d] + b_pre[d];
        enc_in[i] = e;
        Ah[i] = f2bf(e);
        ss += e * e;
    }
    for (int o = 32; o > 0; o >>= 1) ss += __shfl_down(ss, o, 64);
    if ((t & 63) == 0) red[t >> 6] = ss;
    __syncthreads();
    if (t == 0) sigma[b] = sqrtf((red[0] + red[1] + red[2] + red[3]) / (float)D_MODEL);
}

// ---------------------------------------------------------------- dead-feature bitmask
__global__ __launch_bounds__(256) void k_dead(
    const int* __restrict__ act, u64* __restrict__ dmask, float* __restrict__ scal) {
    int f = blockIdx.x * 256 + threadIdx.x;
    bool dead = act[f] > DEAD_AFTER;
    u64 m = __ballot(dead);
    if ((threadIdx.x & 63) == 0) {
        dmask[f >> 6] = m;
        if (m != 0ULL) scal[2] = 1.0f;   // benign race
    }
}

// ---------------------------------------------------------------- W_enc -> Bt hi/lo (transpose + bf16 split)
__global__ __launch_bounds__(256) void k_convB(
    const float* __restrict__ W, u16* __restrict__ Bh, u16* __restrict__ Bl) {
    __shared__ float tile[64][65];
    const int bx = blockIdx.x;            // n tile 0..511
    const int by = blockIdx.y;            // k tile 0..11
    const int tx = threadIdx.x & 63;      // n within tile
    const int ty = threadIdx.x >> 6;      // 0..3
#pragma unroll
    for (int it = 0; it < 16; it++) {
        int k = ty + it * 4;
        tile[k][tx] = W[(size_t)(by * 64 + k) * N_FEAT + bx * 64 + tx];
    }
    __syncthreads();
    const int n  = threadIdx.x >> 2;      // 0..63
    const int kg = threadIdx.x & 3;       // 0..3 (16 k's each)
    u16 h[16], lo[16];
#pragma unroll
    for (int i = 0; i < 16; i++) {
        float v = tile[kg * 16 + i][n];
        h[i]  = f2bf(v);
        lo[i] = f2bf(v - bf2f(h[i]));
    }
    size_t off = (size_t)(bx * 64 + n) * D_MODEL + by * 64 + kg * 16;
    *(short8*)&Bh[off]     = *(short8*)&h[0];
    *(short8*)&Bh[off + 8] = *(short8*)&h[8];
    *(short8*)&Bl[off]     = *(short8*)&lo[0];
    *(short8*)&Bl[off + 8] = *(short8*)&lo[8];
}

// ---------------------------------------------------------------- bf16 MFMA GEMM + fused candidate scan
// Coalesced staging: tiles stored [row][32k] k-fastest; 4 lanes/row -> each
// gll16 touches 16 fully-consumed 64B lines. Double-buffered 32 KB LDS.
__global__ __launch_bounds__(256, 4) void k_gemm(
    const u16* __restrict__ Ah, const u16* __restrict__ Bh,
    const float* __restrict__ sigma, const u64* __restrict__ dmask,
    u64* __restrict__ cand0, int* __restrict__ cnt0,
    u64* __restrict__ cand1, int* __restrict__ cnt1) {
    __shared__ __align__(16) u16 lds[16384];   // 2 bufs x (A 4096 + B 4096 u16) = 32 KB
    const int l  = blockIdx.x;
    const int nx = (l & 7) + ((l >> 6) << 3);  // XCD swizzle: same-nx blocks co-XCD
    const int my = (l >> 3) & 7;
    const int t  = threadIdx.x;
    const int w  = t >> 6, lane = t & 63;
    const int wm = w >> 1, wn = w & 1;
    const int lane15 = lane & 15, quad = lane >> 4;

    // staging: thread t handles chunk t (row t>>2, quarter t&3) and chunk t+256
    const u16* pA = Ah + (size_t)(my * 128 + (t >> 2)) * D_MODEL + (t & 3) * 8;
    const u16* pB = Bh + (size_t)(nx * 128 + (t >> 2)) * D_MODEL + (t & 3) * 8;
    u16* lA = &lds[t * 8];
    u16* lB = &lds[4096 + t * 8];

    auto stage = [&](int k0, int buf) {
        u16* a = lA + buf * 8192;
        u16* b = lB + buf * 8192;
        gll16(pA + k0, a);
        gll16(pA + 64 * D_MODEL + k0, a + 2048);
        gll16(pB + k0, b);
        gll16(pB + 64 * D_MODEL + k0, b + 2048);
    };

    f32x4 acc[4][4];
#pragma unroll
    for (int i = 0; i < 4; i++)
#pragma unroll
        for (int j = 0; j < 4; j++) acc[i][j] = (f32x4){0.f, 0.f, 0.f, 0.f};

    // fragment read: A[m][k]: m = wm*64+i*16+lane15, k-block = quad -> u16 idx m*32+quad*8
    const int abase = (wm * 64 + lane15) * 32 + quad * 8;
    const int bbase = 4096 + (wn * 64 + lane15) * 32 + quad * 8;

    stage(0, 0);
    int cur = 0;
    for (int ks = 0; ks < D_MODEL / 32; ks++) {
        __syncthreads();
        if (ks + 1 < D_MODEL / 32) stage((ks + 1) * 32, cur ^ 1);
        const u16* L = lds + cur * 8192;
        short8 a[4], b[4];
#pragma unroll
        for (int i = 0; i < 4; i++) a[i] = *(const short8*)&L[abase + i * 512];
#pragma unroll
        for (int j = 0; j < 4; j++) b[j] = *(const short8*)&L[bbase + j * 512];
#pragma unroll
        for (int i = 0; i < 4; i++)
#pragma unroll
            for (int j = 0; j < 4; j++)
                acc[i][j] = __builtin_amdgcn_mfma_f32_16x16x32_bf16(a[i], b[j], acc[i][j], 0, 0, 0);
        cur ^= 1;
    }
    // ---- epilogue: threshold scan, no C materialization
    __syncthreads();
    float* srow = (float*)lds;          // 128 floats
    u64*   sdw  = (u64*)&lds[256];      // 2 u64 at byte 512
    if (t < 128) srow[t] = sigma[my * 128 + t];
    if (t == 128) sdw[0] = dmask[nx * 2];
    if (t == 129) sdw[1] = dmask[nx * 2 + 1];
    __syncthreads();
#pragma unroll
    for (int i = 0; i < 4; i++)
#pragma unroll
        for (int j = 0; j < 4; j++)
#pragma unroll
            for (int r = 0; r < 4; r++) {
                int rl = wm * 64 + i * 16 + quad * 4 + r;
                int cl = wn * 64 + j * 16 + lane15;
                float v = acc[i][j][r];
                float sg = srow[rl];
                if (v > 2.0f * sg) {
                    int grow = my * 128 + rl;
                    unsigned gcol = (unsigned)(nx * 128 + cl);
                    u64 key = ((u64)sortable(v) << 32) | (u64)(0xFFFFFFFFu - gcol);
                    if (v > 2.4f * sg) {
                        int p = atomicAdd(&cnt0[grow], 1);
                        if (p < ROWCAP) cand0[(size_t)grow * ROWCAP + p] = key;
                    }
                    if ((sdw[cl >> 6] >> (cl & 63)) & 1ULL) {
                        int p = atomicAdd(&cnt1[grow], 1);
                        if (p < ROWCAP) cand1[(size_t)grow * ROWCAP + p] = key;
                    }
                }
            }
}

// ---------------------------------------------------------------- topk with wide rescue band
__device__ __forceinline__ void bitonic(u64* sbuf, int ns, int t) {
    for (int size = 2; size <= ns; size <<= 1) {
        for (int stride = size >> 1; stride > 0; stride >>= 1) {
            for (int i = t; i < ns; i += 256) {
                int j = i ^ stride;
                if (j > i) {
                    u64 x0 = sbuf[i], x1 = sbuf[j];
                    bool up = ((i & size) == 0);
                    if ((x0 > x1) == up) { sbuf[i] = x1; sbuf[j] = x0; }
                }
            }
            __syncthreads();
        }
    }
}

__global__ __launch_bounds__(256) void k_topk(
    const u64* __restrict__ cand0, const int* __restrict__ cnt0,
    const u64* __restrict__ cand1, const int* __restrict__ cnt1,
    const float* __restrict__ enc_in, const float* __restrict__ W_enc,
    const u16* __restrict__ Bth, const u16* __restrict__ Btl,
    const float* __restrict__ sigma,
    int* __restrict__ tidx, float* __restrict__ tw,
    int* __restrict__ aidx, float* __restrict__ aw) {
    const int b = blockIdx.x, t = threadIdx.x;
    const int w = t >> 6, lane = t & 63;
    __shared__ u64 sbuf[ROWCAP];
    __shared__ int rlist[RESCUE_CAP];
    __shared__ int sh_rcnt;
    const float delta = 0.0125f * sigma[b];   // ~8 sigma of bf16 ranking error

    for (int p = 0; p < 2; p++) {
        const int k = p ? AUX_K : K_TOP;
        const u64* cand = p ? cand1 : cand0;
        int cnt = min(p ? cnt1[b] : cnt0[b], ROWCAP);
        int ns = k; while (ns < cnt) ns <<= 1;
        for (int i = t; i < ns; i += 256) sbuf[i] = (i < cnt) ? cand[(size_t)b * ROWCAP + i] : 0ULL;
        if (t == 0) sh_rcnt = 0;
        __syncthreads();
        bitonic(sbuf, ns, t);   // ascending; top at the end
        // rescue band around the approx rank-k value
        float vk = (cnt >= k) ? unsortable((unsigned)(sbuf[ns - k] >> 32)) : 0.f;
        if (cnt >= k) {
            for (int i = t; i < ns; i += 256) {
                float v = unsortable((unsigned)(sbuf[i] >> 32));  // pads -> NaN -> excluded
                if (fabsf(v - vk) <= delta) {
                    int q = atomicAdd(&sh_rcnt, 1);
                    if (q < RESCUE_CAP) rlist[q] = i;
                }
            }
        }
        __syncthreads();
        int rc = min(sh_rcnt, RESCUE_CAP);
        if (rc >= 2) {   // boundary contested: recompute, wave-parallel
            for (int c = w; c < rc; c += 4) {
                int ip = rlist[c];
                u64 e = sbuf[ip];
                unsigned fi = 0xFFFFFFFFu - (unsigned)(e & 0xFFFFFFFFull);
                float s = 0.f;
                if (p == 0) {
                    // exact f32: true W_enc column (strided gather)
#pragma unroll
                    for (int r = 0; r < 12; r++) {
                        int d = lane + 64 * r;
                        s += enc_in[(size_t)b * D_MODEL + d] * W_enc[(size_t)d * N_FEAT + fi];
                    }
                } else {
                    // hi+lo bf16 row (coalesced), err ~6e-5 — harmless for aux loss
#pragma unroll
                    for (int r = 0; r < 12; r++) {
                        int d = lane + 64 * r;
                        s += enc_in[(size_t)b * D_MODEL + d] *
                             (bf2f(Bth[(size_t)fi * D_MODEL + d]) + bf2f(Btl[(size_t)fi * D_MODEL + d]));
                    }
                }
                for (int o = 32; o > 0; o >>= 1) s += __shfl_down(s, o, 64);
                if (lane == 0)
                    sbuf[ip] = ((u64)sortable(s) << 32) | (e & 0xFFFFFFFFull);
            }
            __syncthreads();
            bitonic(sbuf, ns, t);
        }
        int*   oidx = p ? aidx : tidx;
        float* ow   = p ? aw   : tw;
        for (int s2 = t; s2 < k; s2 += 256) {
            float wv = 0.f; int fi = 0;
            if (s2 < cnt) {
                u64 e = sbuf[ns - 1 - s2];
                wv = unsortable((unsigned)(e >> 32));
                fi = (int)(0xFFFFFFFFu - (unsigned)(e & 0xFFFFFFFFull));
            }
            ow[(size_t)b * k + s2]   = wv;
            oidx[(size_t)b * k + s2] = fi;
        }
        __syncthreads();
    }
}

// ---------------------------------------------------------------- decode (f32 W_dec) + losses
__global__ __launch_bounds__(256) void k_decode(
    const float* __restrict__ Wd, const float* __restrict__ xn,
    const int* __restrict__ tidx, const float* __restrict__ tw,
    const int* __restrict__ aidx, const float* __restrict__ aw,
    const float* __restrict__ b_post, const float* __restrict__ avg,
    float* __restrict__ scal,
    float* __restrict__ y, float* __restrict__ loss) {
    const int b = blockIdx.x, t = threadIdx.x;
    __shared__ float sw[K_TOP];   __shared__ int sidx[K_TOP];
    __shared__ float saw[AUX_K];  __shared__ int saidx[AUX_K];
    __shared__ float red1[4], red2[4], red3[4];
    if (t < K_TOP) { sw[t] = tw[(size_t)b * K_TOP + t]; sidx[t] = tidx[(size_t)b * K_TOP + t]; }
    else if (t < K_TOP + AUX_K) {
        int j = t - K_TOP;
        saw[j] = aw[(size_t)b * AUX_K + j]; saidx[j] = aidx[(size_t)b * AUX_K + j];
    }
    __syncthreads();
    const float inv = avg[0] / sqrtf((float)D_MODEL);
    float rsum = 0.f, asum = 0.f, xsum = 0.f;
#pragma unroll
    for (int c = 0; c < 3; c++) {
        const int d = t + 256 * c;
        float acc = 0.f;
#pragma unroll 8
        for (int j = 0; j < K_TOP; j++)
            acc = fmaf(sw[j], Wd[(size_t)sidx[j] * D_MODEL + d], acc);
        float yn = acc + b_post[d];
        float aacc = 0.f;
#pragma unroll 8
        for (int j = 0; j < AUX_K; j++)
            aacc = fmaf(saw[j], Wd[(size_t)saidx[j] * D_MODEL + d], aacc);
        float xv = xn[(size_t)b * D_MODEL + d];
        float r = xv - yn;
        rsum += r * r;
        float ar = yn - xv - aacc;
        asum += ar * ar;
        xsum += xv * xv;
        y[(size_t)b * D_MODEL + d] = yn * inv;
    }
    for (int o = 32; o > 0; o >>= 1) {
        rsum += __shfl_down(rsum, o, 64);
        asum += __shfl_down(asum, o, 64);
        xsum += __shfl_down(xsum, o, 64);
    }
    if ((t & 63) == 0) { int ww = t >> 6; red1[ww] = rsum; red2[ww] = asum; red3[ww] = xsum; }
    __syncthreads();
    if (t == 0) {
        float R = red1[0] + red1[1] + red1[2] + red1[3];
        float A = red2[0] + red2[1] + red2[2] + red2[3];
        float X = red3[0] + red3[1] + red3[2] + red3[3];
        loss[b] = R / (float)D_MODEL + AUX_COEFF * (scal[2] > 0.f ? A / (float)D_MODEL : 0.f);
        atomicAdd(&scal[0], R);
        atomicAdd(&scal[1], X);
    }
}

__global__ void k_fin(const float* __restrict__ scal, float* __restrict__ fvu_out) {
    *fvu_out = scal[0] / scal[1];
}

// ---------------------------------------------------------------- launch
extern "C" void kernel_launch(void* const* d_in, const int* in_sizes, int n_in,
                              void* d_out, int out_size, void* d_ws, size_t ws_size,
                              hipStream_t stream) {
    const float* x      = (const float*)d_in[0];
    const float* W_enc  = (const float*)d_in[1];
    const float* W_dec  = (const float*)d_in[2];
    const float* b_pre  = (const float*)d_in[3];
    const float* b_post = (const float*)d_in[4];
    const float* avg    = (const float*)d_in[5];
    const int*   act    = (const int*)d_in[6];

    char* base = (char*)d_ws;
    const size_t OFF_XN    = 0;
    const size_t OFF_ENCIN = 3145728;
    const size_t OFF_SIGMA = 6291456;
    const size_t OFF_AH    = 6295552;
    const size_t OFF_CNT0  = 7868416;
    const size_t OFF_CNT1  = 7872512;
    const size_t OFF_DMASK = 7876608;
    const size_t OFF_SCAL  = 7880704;
    const size_t OFF_TW    = 7880960;
    const size_t OFF_TIDX  = 8143104;
    const size_t OFF_AW    = 8405248;
    const size_t OFF_AIDX  = 8929536;
    const size_t OFF_CAND0 = 9453824;
    const size_t OFF_CAND1 = 17842432;
    const size_t OFF_BTH   = 26231040;
    const size_t OFF_BTL   = 76562688;   // end ~126.9 MB

    float* xn     = (float*)(base + OFF_XN);
    float* enc_in = (float*)(base + OFF_ENCIN);
    float* sigma  = (float*)(base + OFF_SIGMA);
    u16*   Ah     = (u16*)(base + OFF_AH);
    int*   cnt0   = (int*)(base + OFF_CNT0);
    int*   cnt1   = (int*)(base + OFF_CNT1);
    u64*   dmask  = (u64*)(base + OFF_DMASK);
    float* scal   = (float*)(base + OFF_SCAL);
    float* tw     = (float*)(base + OFF_TW);
    int*   tidx   = (int*)(base + OFF_TIDX);
    float* aw     = (float*)(base + OFF_AW);
    int*   aidx   = (int*)(base + OFF_AIDX);
    u64*   cand0  = (u64*)(base + OFF_CAND0);
    u64*   cand1  = (u64*)(base + OFF_CAND1);
    u16*   Bth    = (u16*)(base + OFF_BTH);
    u16*   Btl    = (u16*)(base + OFF_BTL);

    float* y    = (float*)d_out;
    float* loss = y + (size_t)BATCH * D_MODEL;
    float* fvu  = loss + BATCH;

    hipMemsetAsync(base + OFF_CNT0, 0, 12544, stream);  // cnt0+cnt1+dmask+scal

    k_prep<<<BATCH, 256, 0, stream>>>(x, b_pre, b_post, avg, xn, enc_in, Ah, sigma);
    k_dead<<<N_FEAT / 256, 256, 0, stream>>>(act, dmask, scal);
    k_convB<<<dim3(N_FEAT / 64, D_MODEL / 64), 256, 0, stream>>>(W_enc, Bth, Btl);
    k_gemm<<<(N_FEAT / 128) * (BATCH / 128), 256, 0, stream>>>(
        Ah, Bth, sigma, dmask, cand0, cnt0, cand1, cnt1);
    k_topk<<<BATCH, 256, 0, stream>>>(cand0, cnt0, cand1, cnt1, enc_in, W_enc, Bth, Btl,
                                      sigma, tidx, tw, aidx, aw);
    k_decode<<<BATCH, 256, 0, stream>>>(W_dec, xn, tidx, tw, aidx, aw, b_post, avg, scal, y, loss);
    k_fin<<<1, 1, 0, stream>>>(scal, fvu);
}